// Round 6
// baseline (156.617 us; speedup 1.0000x reference)
//
#include <hip/hip_runtime.h>
#include <hip/hip_bf16.h>
#include <math.h>

#define HIDDEN 1024
#define HEADS 16
#define DK 64
#define BB 2
#define SS 2048
#define MROWS (BB*SS)  /* 4096 */

typedef __attribute__((ext_vector_type(8))) short short8;
typedef __attribute__((ext_vector_type(4))) float f32x4;
typedef __attribute__((ext_vector_type(4))) unsigned short ushort4_t;

static __device__ __forceinline__ unsigned short f2bf(float f) {
    unsigned int u = __float_as_uint(f);
    u += 0x7fffu + ((u >> 16) & 1u);
    return (unsigned short)(u >> 16);
}

static __device__ __forceinline__ unsigned int cvtpk(float lo, float hi) {
    unsigned int r;
    asm volatile("v_cvt_pk_bf16_f32 %0, %1, %2" : "=v"(r) : "v"(lo), "v"(hi));
    return r;
}
// pack 8 f32 (two float4) -> short8 of bf16, pure register bitcast (no TBAA hazard)
static __device__ __forceinline__ short8 pack_bf16x8(float4 lo, float4 hi) {
    union { unsigned int u[4]; short8 s; } r;
    r.u[0] = cvtpk(lo.x, lo.y);
    r.u[1] = cvtpk(lo.z, lo.w);
    r.u[2] = cvtpk(hi.x, hi.y);
    r.u[3] = cvtpk(hi.z, hi.w);
    return r.s;
}

// ---------------------------------------------------------------- batched QKV projection GEMM (fused f32->bf16 cast)
// grid (8, 32, 3): z=0 -> Q (scatter [B,H,S,D], scaled), z=1 -> K, z=2 -> V ([B,H,D,S]).
// A (query/key/value) and W are read as fp32 and converted during LDS staging.
__global__ __launch_bounds__(256, 3) void gemm_qkv(
    const float* __restrict__ Xq, const float* __restrict__ Xk, const float* __restrict__ Xv,
    const float* __restrict__ Wq, const float* __restrict__ Wk, const float* __restrict__ Wv,
    const float* __restrict__ bq, const float* __restrict__ bk, const float* __restrict__ bv,
    unsigned short* __restrict__ Qb, unsigned short* __restrict__ Kb, unsigned short* __restrict__ Vt,
    float scale_q) {
    __shared__ unsigned short As[128][40];
    __shared__ unsigned short Bs[128][40];
    const int z = blockIdx.z;
    const float* A  = (z == 0) ? Xq : (z == 1) ? Xk : Xv;
    const float* Wt = (z == 0) ? Wq : (z == 1) ? Wk : Wv;
    const float* bias = (z == 0) ? bq : (z == 1) ? bk : bv;
    unsigned short* O = (z == 0) ? Qb : (z == 1) ? Kb : Vt;
    const float oscale = (z == 0) ? scale_q : 1.0f;

    const int t    = threadIdx.x;
    const int lane = t & 63;
    const int wave = t >> 6;
    const int m0 = blockIdx.y * 128;
    const int n0 = blockIdx.x * 128;
    const int row  = t >> 2;
    const int col8 = (t & 3) * 8;

    const int wm = (wave >> 1) * 64;
    const int wn = (wave & 1) * 64;
    const int lr = lane & 15;
    const int lk = (lane >> 4) * 8;

    f32x4 acc[4][4];
#pragma unroll
    for (int i = 0; i < 4; i++)
#pragma unroll
        for (int j = 0; j < 4; j++) acc[i][j] = f32x4{0.f, 0.f, 0.f, 0.f};

    for (int k0 = 0; k0 < HIDDEN; k0 += 32) {
        const float* a0 = A  + (size_t)(m0 + row) * HIDDEN + k0 + col8;
        const float* a1 = A  + (size_t)(m0 + row + 64) * HIDDEN + k0 + col8;
        const float* w0 = Wt + (size_t)(n0 + row) * HIDDEN + k0 + col8;
        const float* w1 = Wt + (size_t)(n0 + row + 64) * HIDDEN + k0 + col8;
        float4 a00 = reinterpret_cast<const float4*>(a0)[0];
        float4 a01 = reinterpret_cast<const float4*>(a0)[1];
        float4 a10 = reinterpret_cast<const float4*>(a1)[0];
        float4 a11 = reinterpret_cast<const float4*>(a1)[1];
        float4 w00 = reinterpret_cast<const float4*>(w0)[0];
        float4 w01 = reinterpret_cast<const float4*>(w0)[1];
        float4 w10 = reinterpret_cast<const float4*>(w1)[0];
        float4 w11 = reinterpret_cast<const float4*>(w1)[1];
        __syncthreads();
        *reinterpret_cast<short8*>(&As[row][col8])      = pack_bf16x8(a00, a01);
        *reinterpret_cast<short8*>(&As[row + 64][col8]) = pack_bf16x8(a10, a11);
        *reinterpret_cast<short8*>(&Bs[row][col8])      = pack_bf16x8(w00, w01);
        *reinterpret_cast<short8*>(&Bs[row + 64][col8]) = pack_bf16x8(w10, w11);
        __syncthreads();
        short8 af[4], bfr[4];
#pragma unroll
        for (int i = 0; i < 4; i++) af[i]  = *reinterpret_cast<const short8*>(&As[wm + i * 16 + lr][lk]);
#pragma unroll
        for (int j = 0; j < 4; j++) bfr[j] = *reinterpret_cast<const short8*>(&Bs[wn + j * 16 + lr][lk]);
#pragma unroll
        for (int i = 0; i < 4; i++)
#pragma unroll
            for (int j = 0; j < 4; j++)
                acc[i][j] = __builtin_amdgcn_mfma_f32_16x16x32_bf16(af[i], bfr[j], acc[i][j], 0, 0, 0);
    }

#pragma unroll
    for (int i = 0; i < 4; i++) {
        int mrow = m0 + wm + i * 16 + (lane >> 4) * 4;
#pragma unroll
        for (int j = 0; j < 4; j++) {
            int ncol = n0 + wn + j * 16 + lr;
            float bv = bias[ncol];
            int b_ = mrow >> 11;
            int h_ = ncol >> 6;
            int d_ = ncol & 63;
            if (z != 2) {   // Q/K: [B,H,S,D]
#pragma unroll
                for (int r = 0; r < 4; r++) {
                    int s_ = (mrow + r) & 2047;
                    O[(((size_t)(b_ * HEADS + h_)) * SS + s_) * DK + d_] = f2bf((acc[i][j][r] + bv) * oscale);
                }
            } else {        // V: [B,H,D,S] pre-transposed; 4 regs consecutive s -> 8B store
                int s0 = mrow & 2047;
                ushort4_t pk;
                pk.x = f2bf(acc[i][j][0] + bv);
                pk.y = f2bf(acc[i][j][1] + bv);
                pk.z = f2bf(acc[i][j][2] + bv);
                pk.w = f2bf(acc[i][j][3] + bv);
                *reinterpret_cast<ushort4_t*>(O + (((size_t)(b_ * HEADS + h_) * DK + d_) * SS + s0)) = pk;
            }
        }
    }
}

// ---------------------------------------------------------------- final O-projection GEMM, 128x64 tile
// A = Yb bf16; W = w_o fp32 converted during staging. out fp32 [M,N]. 512 blocks.
__global__ __launch_bounds__(256) void gemm_o(const unsigned short* __restrict__ A,
                                              const float* __restrict__ Wt,
                                              const float* __restrict__ bias,
                                              float* __restrict__ O) {
    __shared__ unsigned short As[128][40];
    __shared__ unsigned short Bs[64][40];
    const int t    = threadIdx.x;
    const int lane = t & 63;
    const int wave = t >> 6;
    const int m0 = blockIdx.y * 128;
    const int n0 = blockIdx.x * 64;
    const int row  = t >> 2;        // 0..63
    const int col8 = (t & 3) * 8;

    const int wm = wave * 32;       // 4 waves stacked on M; each wave 32x64 output
    const int lr = lane & 15;
    const int lk = (lane >> 4) * 8;

    f32x4 acc[2][4];
#pragma unroll
    for (int i = 0; i < 2; i++)
#pragma unroll
        for (int j = 0; j < 4; j++) acc[i][j] = f32x4{0.f, 0.f, 0.f, 0.f};

    for (int k0 = 0; k0 < HIDDEN; k0 += 32) {
        short8 av0 = *reinterpret_cast<const short8*>(A + (size_t)(m0 + row)      * HIDDEN + k0 + col8);
        short8 av1 = *reinterpret_cast<const short8*>(A + (size_t)(m0 + row + 64) * HIDDEN + k0 + col8);
        const float* w0 = Wt + (size_t)(n0 + row) * HIDDEN + k0 + col8;
        float4 w00 = reinterpret_cast<const float4*>(w0)[0];
        float4 w01 = reinterpret_cast<const float4*>(w0)[1];
        __syncthreads();
        *reinterpret_cast<short8*>(&As[row][col8])      = av0;
        *reinterpret_cast<short8*>(&As[row + 64][col8]) = av1;
        *reinterpret_cast<short8*>(&Bs[row][col8])      = pack_bf16x8(w00, w01);
        __syncthreads();
        short8 af[2], bfr[4];
#pragma unroll
        for (int i = 0; i < 2; i++) af[i]  = *reinterpret_cast<const short8*>(&As[wm + i * 16 + lr][lk]);
#pragma unroll
        for (int j = 0; j < 4; j++) bfr[j] = *reinterpret_cast<const short8*>(&Bs[j * 16 + lr][lk]);
#pragma unroll
        for (int i = 0; i < 2; i++)
#pragma unroll
            for (int j = 0; j < 4; j++)
                acc[i][j] = __builtin_amdgcn_mfma_f32_16x16x32_bf16(af[i], bfr[j], acc[i][j], 0, 0, 0);
    }

#pragma unroll
    for (int i = 0; i < 2; i++) {
        int mrow = m0 + wm + i * 16 + (lane >> 4) * 4;
#pragma unroll
        for (int j = 0; j < 4; j++) {
            int ncol = n0 + j * 16 + lr;
            float bv = bias[ncol];
#pragma unroll
            for (int r = 0; r < 4; r++)
                O[(size_t)(mrow + r) * HIDDEN + ncol] = acc[i][j][r] + bv;
        }
    }
}

// ---------------------------------------------------------------- flash attention v6
// v5 restructured for occupancy: 64 q/block (16 q/wave), grid 1024 blocks, LDS 40KB
// -> 4 blocks/CU, 16 waves/CU. XCD-aware bijective bh grouping (4 heads per XCD slice).
// LDS-shared K/V (double-buffered, global_load_lds, both-sides XOR swizzle),
// swapped-operand MFMA; Psh [4][16][64] XOR-swizzled.
// Q:[B,H,S,D] bf16 PRE-SCALED by 0.125*log2e; K:[B,H,S,D]; Vt:[B,H,D,S]; Y:[B,S,HIDDEN] bf16.
__global__ __launch_bounds__(256, 4) void attn_kernel(const unsigned short* __restrict__ Qb,
                                                      const unsigned short* __restrict__ Kb,
                                                      const unsigned short* __restrict__ Vt,
                                                      unsigned short* __restrict__ Yb) {
    __shared__ __attribute__((aligned(16))) unsigned short Ksh[2][64 * 64];
    __shared__ __attribute__((aligned(16))) unsigned short Vsh[2][64 * 64];
    __shared__ __attribute__((aligned(16))) unsigned short Psh[4][16][64];   // per-wave P, XOR-swizzled

    const int t    = threadIdx.x;
    const int lane = t & 63;
    const int wave = t >> 6;
    // bijective XCD grouping: fid%8 = XCD slot; each slot covers 4 consecutive-ish heads
    const int fid  = blockIdx.y * gridDim.x + blockIdx.x;   // dispatch-linear id, 0..1023
    const int qblk = (fid >> 3) & 31;
    const int bh   = (fid & 7) * 4 + (fid >> 8);
    const int b_ = bh >> 4, h_ = bh & 15;
    const int qbase = qblk * 64 + wave * 16;
    const unsigned short* Qp = Qb + (size_t)bh * SS * DK;
    const unsigned short* Kp = Kb + (size_t)bh * SS * DK;
    const unsigned short* Vp = Vt + (size_t)bh * DK * SS;
    const int lr = lane & 15;
    const int g  = lane >> 4;

    // staging mapping: lane i writes LDS row (base + i>>3), chunk (i&7);
    // source chunk pre-swizzled so that swizzled ds_read returns linear data.
    const int sr = lane >> 3;                 // 0..7 row-within-8
    const int cs = (lane & 7) ^ sr;           // source 16B chunk

    // Q B-frags (q col qbase+lr, d halves)
    short8 bq[2];
#pragma unroll
    for (int dh = 0; dh < 2; dh++)
        bq[dh] = *reinterpret_cast<const short8*>(
            Qp + (size_t)(qbase + lr) * DK + dh * 32 + g * 8);

    f32x4 accd[4];
#pragma unroll
    for (int dt = 0; dt < 4; dt++) accd[dt] = f32x4{0.f, 0.f, 0.f, 0.f};
    float mi = -INFINITY, li = 0.f;

#define STAGE(BUF, KV0) do {                                                                 \
    __builtin_amdgcn_global_load_lds(                                                        \
        (const __attribute__((address_space(1))) unsigned int*)(Kp + (size_t)((KV0) + wave * 16 + sr) * DK + cs * 8), \
        (__attribute__((address_space(3))) unsigned int*)&Ksh[BUF][(wave * 16) * 64], 16, 0, 0); \
    __builtin_amdgcn_global_load_lds(                                                        \
        (const __attribute__((address_space(1))) unsigned int*)(Kp + (size_t)((KV0) + wave * 16 + 8 + sr) * DK + cs * 8), \
        (__attribute__((address_space(3))) unsigned int*)&Ksh[BUF][(wave * 16 + 8) * 64], 16, 0, 0); \
    __builtin_amdgcn_global_load_lds(                                                        \
        (const __attribute__((address_space(1))) unsigned int*)(Vp + (size_t)(wave * 16 + sr) * SS + (KV0) + cs * 8), \
        (__attribute__((address_space(3))) unsigned int*)&Vsh[BUF][(wave * 16) * 64], 16, 0, 0); \
    __builtin_amdgcn_global_load_lds(                                                        \
        (const __attribute__((address_space(1))) unsigned int*)(Vp + (size_t)(wave * 16 + 8 + sr) * SS + (KV0) + cs * 8), \
        (__attribute__((address_space(3))) unsigned int*)&Vsh[BUF][(wave * 16 + 8) * 64], 16, 0, 0); \
} while (0)

    STAGE(0, 0);
    __syncthreads();

    for (int kv0 = 0; kv0 < SS; kv0 += 64) {
        const int cur = (kv0 >> 6) & 1;
        if (kv0 + 64 < SS) STAGE(cur ^ 1, kv0 + 64);

        // K frags: row kv = tt*16+lr, d-chunk (h*4+g) XOR-swizzled by row
        short8 kf[4][2];
#pragma unroll
        for (int tt = 0; tt < 4; tt++)
#pragma unroll
            for (int h = 0; h < 2; h++)
                kf[tt][h] = *reinterpret_cast<const short8*>(
                    &Ksh[cur][(tt * 16 + lr) * 64 + (((h * 4 + g) ^ (lr & 7)) << 3)]);

        // QK^T -> S^T[kv][q]: lane holds kv = tt*16 + 4g + r for q-col = lr
        f32x4 sv[4];
#pragma unroll
        for (int tt = 0; tt < 4; tt++) {
            f32x4 z = f32x4{0.f, 0.f, 0.f, 0.f};
            z = __builtin_amdgcn_mfma_f32_16x16x32_bf16(kf[tt][0], bq[0], z, 0, 0, 0);
            z = __builtin_amdgcn_mfma_f32_16x16x32_bf16(kf[tt][1], bq[1], z, 0, 0, 0);
            sv[tt] = z;
        }

        // online softmax (exp2 domain)
        float vmax = sv[0][0];
#pragma unroll
        for (int tt = 0; tt < 4; tt++)
#pragma unroll
            for (int r = 0; r < 4; r++) vmax = fmaxf(vmax, sv[tt][r]);
        vmax = fmaxf(vmax, __shfl_xor(vmax, 16));
        vmax = fmaxf(vmax, __shfl_xor(vmax, 32));
        if (!__all(vmax <= mi + 8.0f)) {
            float mnew = fmaxf(mi, vmax);
            float sc = __builtin_amdgcn_exp2f(mi - mnew);
            li *= sc;
#pragma unroll
            for (int dt = 0; dt < 4; dt++)
#pragma unroll
                for (int r = 0; r < 4; r++) accd[dt][r] *= sc;
            mi = mnew;
        }
        float p[16];
        float rs = 0.f;
#pragma unroll
        for (int tt = 0; tt < 4; tt++)
#pragma unroll
            for (int r = 0; r < 4; r++) {
                p[tt * 4 + r] = __builtin_amdgcn_exp2f(sv[tt][r] - mi);
                rs += p[tt * 4 + r];
            }
        rs += __shfl_xor(rs, 16);
        rs += __shfl_xor(rs, 32);
        li += rs;
        // pack P[kv][q]: row q = lr, kv byte 32tt+8g -> 16B chunk (2tt+(g>>1)) ^ (lr&7),
        // 8B half g&1. ushort4_t store (element-compatible TBAA with short8 reads).
#pragma unroll
        for (int tt = 0; tt < 4; tt++) {
            ushort4_t pk;
            pk.x = f2bf(p[tt * 4 + 0]);
            pk.y = f2bf(p[tt * 4 + 1]);
            pk.z = f2bf(p[tt * 4 + 2]);
            pk.w = f2bf(p[tt * 4 + 3]);
            int cw = (2 * tt + (g >> 1)) ^ (lr & 7);
            *reinterpret_cast<ushort4_t*>(&Psh[wave][lr][cw * 8 + (g & 1) * 4]) = pk;
        }

        // fence: P-writes above must not be reordered against pf reads below
        __builtin_amdgcn_sched_barrier(0);

        // P B-frags: unswizzled chunk h*4+g of row q, same XOR
        short8 pf[2];
#pragma unroll
        for (int h = 0; h < 2; h++)
            pf[h] = *reinterpret_cast<const short8*>(
                &Psh[wave][lr][((h * 4 + g) ^ (lr & 7)) * 8]);

        // PV: accd[dt] += V^T[d][kv] * P[kv][q]
#pragma unroll
        for (int dt = 0; dt < 4; dt++) {
            short8 vf0 = *reinterpret_cast<const short8*>(
                &Vsh[cur][(dt * 16 + lr) * 64 + ((g ^ (lr & 7)) << 3)]);
            short8 vf1 = *reinterpret_cast<const short8*>(
                &Vsh[cur][(dt * 16 + lr) * 64 + (((4 + g) ^ (lr & 7)) << 3)]);
            accd[dt] = __builtin_amdgcn_mfma_f32_16x16x32_bf16(vf0, pf[0], accd[dt], 0, 0, 0);
            accd[dt] = __builtin_amdgcn_mfma_f32_16x16x32_bf16(vf1, pf[1], accd[dt], 0, 0, 0);
        }
        __syncthreads();
    }
#undef STAGE

    float inv = 1.0f / li;
    size_t ob = ((size_t)b_ * SS + qbase + lr) * HIDDEN + h_ * 64 + g * 4;
#pragma unroll
    for (int dt = 0; dt < 4; dt++) {
        ushort4_t o;
        o.x = f2bf(accd[dt][0] * inv);
        o.y = f2bf(accd[dt][1] * inv);
        o.z = f2bf(accd[dt][2] * inv);
        o.w = f2bf(accd[dt][3] * inv);
        *reinterpret_cast<ushort4_t*>(Yb + ob + dt * 16) = o;
    }
}

// ---------------------------------------------------------------- launch
extern "C" void kernel_launch(void* const* d_in, const int* in_sizes, int n_in,
                              void* d_out, int out_size, void* d_ws, size_t ws_size,
                              hipStream_t stream) {
    const float* query = (const float*)d_in[0];
    const float* key_  = (const float*)d_in[1];
    const float* value = (const float*)d_in[2];
    const float* w_q = (const float*)d_in[3];
    const float* b_q = (const float*)d_in[4];
    const float* w_k = (const float*)d_in[5];
    const float* b_k = (const float*)d_in[6];
    const float* w_v = (const float*)d_in[7];
    const float* b_v = (const float*)d_in[8];
    const float* w_o = (const float*)d_in[9];
    const float* b_o = (const float*)d_in[10];

    const size_t SZ_X = (size_t)MROWS * HIDDEN * 2;   // 8 MiB (bf16)
    char* ws = (char*)d_ws;
    unsigned short* Qb  = (unsigned short*)(ws);
    unsigned short* Kbf = (unsigned short*)(ws + SZ_X);
    unsigned short* Vt  = (unsigned short*)(ws + 2 * SZ_X);
    unsigned short* Yb  = (unsigned short*)(ws + 3 * SZ_X);

    const float SCALE_Q = 0.125f * 1.4426950408889634f;  // 1/sqrt(64) * log2(e), folded into Q
    gemm_qkv<<<dim3(HIDDEN / 128, MROWS / 128, 3), 256, 0, stream>>>(
        query, key_, value, w_q, w_k, w_v, b_q, b_k, b_v, Qb, Kbf, Vt, SCALE_Q);

    attn_kernel<<<dim3(SS / 64, BB * HEADS), 256, 0, stream>>>(Qb, Kbf, Vt, Yb);

    gemm_o<<<dim3(HIDDEN / 64, MROWS / 128), 256, 0, stream>>>(Yb, w_o, b_o, (float*)d_out);
}

// Round 7
// 156.518 us; speedup vs baseline: 1.0006x; 1.0006x over previous
//
#include <hip/hip_runtime.h>
#include <hip/hip_bf16.h>
#include <math.h>

#define HIDDEN 1024
#define HEADS 16
#define DK 64
#define BB 2
#define SS 2048
#define MROWS (BB*SS)  /* 4096 */

typedef __attribute__((ext_vector_type(8))) short short8;
typedef __attribute__((ext_vector_type(4))) float f32x4;
typedef __attribute__((ext_vector_type(4))) unsigned short ushort4_t;

static __device__ __forceinline__ unsigned short f2bf(float f) {
    unsigned int u = __float_as_uint(f);
    u += 0x7fffu + ((u >> 16) & 1u);
    return (unsigned short)(u >> 16);
}

static __device__ __forceinline__ unsigned int cvtpk(float lo, float hi) {
    unsigned int r;
    asm volatile("v_cvt_pk_bf16_f32 %0, %1, %2" : "=v"(r) : "v"(lo), "v"(hi));
    return r;
}

// ---------------------------------------------------------------- cast fp32 -> bf16 (X q/k/v + W q/k/v)
__global__ __launch_bounds__(256) void cast_all(
    const float* __restrict__ q, const float* __restrict__ k, const float* __restrict__ v,
    const float* __restrict__ wq, const float* __restrict__ wk, const float* __restrict__ wv,
    unsigned short* __restrict__ Xq, unsigned short* __restrict__ Xk, unsigned short* __restrict__ Xv,
    unsigned short* __restrict__ Wq, unsigned short* __restrict__ Wk, unsigned short* __restrict__ Wv) {
    int i = blockIdx.x * 256 + threadIdx.x;   // float4 index; grid exact: 3*2^20 + 3*2^18
    const float* src; unsigned short* dst; int off;
    if (i < (3 << 20)) {
        int w = i >> 20; off = i & ((1 << 20) - 1);
        src = (w == 0) ? q : (w == 1) ? k : v;
        dst = (w == 0) ? Xq : (w == 1) ? Xk : Xv;
    } else {
        int j = i - (3 << 20);
        int w = j >> 18; off = j & ((1 << 18) - 1);
        src = (w == 0) ? wq : (w == 1) ? wk : wv;
        dst = (w == 0) ? Wq : (w == 1) ? Wk : Wv;
    }
    float4 f = reinterpret_cast<const float4*>(src)[off];
    ushort4_t o;
    o.x = f2bf(f.x); o.y = f2bf(f.y); o.z = f2bf(f.z); o.w = f2bf(f.w);
    reinterpret_cast<ushort4_t*>(dst)[off] = o;
}

// ---------------------------------------------------------------- batched QKV projection GEMM (bf16 in)
// 768 blocks, XCD-swizzled: XCD c gets 12 (m,z)-bands x 8 n-blocks so all n-blocks
// sharing an A-band hit the same L2. z=0 Q (scaled, [B,H,S,D]), z=1 K, z=2 V ([B,H,D,S]).
__global__ __launch_bounds__(256, 3) void gemm_qkv(
    const unsigned short* __restrict__ Xq, const unsigned short* __restrict__ Xk, const unsigned short* __restrict__ Xv,
    const unsigned short* __restrict__ Wq, const unsigned short* __restrict__ Wk, const unsigned short* __restrict__ Wv,
    const float* __restrict__ bq, const float* __restrict__ bk, const float* __restrict__ bv,
    unsigned short* __restrict__ Qb, unsigned short* __restrict__ Kb, unsigned short* __restrict__ Vt,
    float scale_q) {
    __shared__ unsigned short As[128][40];
    __shared__ unsigned short Bs[128][40];
    // bijective remap: lid = x + 8y + 256z (0..767); c=lid&7 -> XCD; band n-fastest
    const int lid = blockIdx.x + 8 * (blockIdx.y + 32 * blockIdx.z);
    const int c = lid & 7, i2 = lid >> 3;         // i2: 0..95
    const int nb = i2 & 7;
    const int band = c * 12 + (i2 >> 3);          // 0..95
    const int yb = band & 31;
    const int z  = band >> 5;                     // 0..2
    const unsigned short* A  = (z == 0) ? Xq : (z == 1) ? Xk : Xv;
    const unsigned short* Wt = (z == 0) ? Wq : (z == 1) ? Wk : Wv;
    const float* bias = (z == 0) ? bq : (z == 1) ? bk : bv;
    unsigned short* O = (z == 0) ? Qb : (z == 1) ? Kb : Vt;
    const float oscale = (z == 0) ? scale_q : 1.0f;

    const int t    = threadIdx.x;
    const int lane = t & 63;
    const int wave = t >> 6;
    const int m0 = yb * 128;
    const int n0 = nb * 128;
    const int row  = t >> 2;
    const int col8 = (t & 3) * 8;

    const int wm = (wave >> 1) * 64;
    const int wn = (wave & 1) * 64;
    const int lr = lane & 15;
    const int lk = (lane >> 4) * 8;

    f32x4 acc[4][4];
#pragma unroll
    for (int i = 0; i < 4; i++)
#pragma unroll
        for (int j = 0; j < 4; j++) acc[i][j] = f32x4{0.f, 0.f, 0.f, 0.f};

    for (int k0 = 0; k0 < HIDDEN; k0 += 32) {
        short8 av0 = *reinterpret_cast<const short8*>(A  + (size_t)(m0 + row)      * HIDDEN + k0 + col8);
        short8 av1 = *reinterpret_cast<const short8*>(A  + (size_t)(m0 + row + 64) * HIDDEN + k0 + col8);
        short8 bv0 = *reinterpret_cast<const short8*>(Wt + (size_t)(n0 + row)      * HIDDEN + k0 + col8);
        short8 bv1 = *reinterpret_cast<const short8*>(Wt + (size_t)(n0 + row + 64) * HIDDEN + k0 + col8);
        __syncthreads();
        *reinterpret_cast<short8*>(&As[row][col8])      = av0;
        *reinterpret_cast<short8*>(&As[row + 64][col8]) = av1;
        *reinterpret_cast<short8*>(&Bs[row][col8])      = bv0;
        *reinterpret_cast<short8*>(&Bs[row + 64][col8]) = bv1;
        __syncthreads();
        short8 af[4], bfr[4];
#pragma unroll
        for (int i = 0; i < 4; i++) af[i]  = *reinterpret_cast<const short8*>(&As[wm + i * 16 + lr][lk]);
#pragma unroll
        for (int j = 0; j < 4; j++) bfr[j] = *reinterpret_cast<const short8*>(&Bs[wn + j * 16 + lr][lk]);
#pragma unroll
        for (int i = 0; i < 4; i++)
#pragma unroll
            for (int j = 0; j < 4; j++)
                acc[i][j] = __builtin_amdgcn_mfma_f32_16x16x32_bf16(af[i], bfr[j], acc[i][j], 0, 0, 0);
    }

#pragma unroll
    for (int i = 0; i < 4; i++) {
        int mrow = m0 + wm + i * 16 + (lane >> 4) * 4;
#pragma unroll
        for (int j = 0; j < 4; j++) {
            int ncol = n0 + wn + j * 16 + lr;
            float bvv = bias[ncol];
            int b_ = mrow >> 11;
            int h_ = ncol >> 6;
            int d_ = ncol & 63;
            if (z != 2) {   // Q/K: [B,H,S,D]
#pragma unroll
                for (int r = 0; r < 4; r++) {
                    int s_ = (mrow + r) & 2047;
                    O[(((size_t)(b_ * HEADS + h_)) * SS + s_) * DK + d_] = f2bf((acc[i][j][r] + bvv) * oscale);
                }
            } else {        // V: [B,H,D,S] pre-transposed
                int s0 = mrow & 2047;
                ushort4_t pk;
                pk.x = f2bf(acc[i][j][0] + bvv);
                pk.y = f2bf(acc[i][j][1] + bvv);
                pk.z = f2bf(acc[i][j][2] + bvv);
                pk.w = f2bf(acc[i][j][3] + bvv);
                *reinterpret_cast<ushort4_t*>(O + (((size_t)(b_ * HEADS + h_) * DK + d_) * SS + s0)) = pk;
            }
        }
    }
}

// ---------------------------------------------------------------- final O-projection GEMM, 128x64 tile
// A = Yb bf16; W = w_o fp32 converted during staging. out fp32 [M,N]. 512 blocks, XCD-swizzled.
__global__ __launch_bounds__(256) void gemm_o(const unsigned short* __restrict__ A,
                                              const float* __restrict__ Wt,
                                              const float* __restrict__ bias,
                                              float* __restrict__ O) {
    __shared__ unsigned short As[128][40];
    __shared__ unsigned short Bs[64][40];
    const int lid = blockIdx.x + 16 * blockIdx.y;   // 0..511
    const int c = lid & 7, i2 = lid >> 3;           // i2: 0..63
    const int nb = i2 & 15;
    const int band = c * 4 + (i2 >> 4);             // 0..31
    const int t    = threadIdx.x;
    const int lane = t & 63;
    const int wave = t >> 6;
    const int m0 = band * 128;
    const int n0 = nb * 64;
    const int row  = t >> 2;
    const int col8 = (t & 3) * 8;

    const int wm = wave * 32;
    const int lr = lane & 15;
    const int lk = (lane >> 4) * 8;

    f32x4 acc[2][4];
#pragma unroll
    for (int i = 0; i < 2; i++)
#pragma unroll
        for (int j = 0; j < 4; j++) acc[i][j] = f32x4{0.f, 0.f, 0.f, 0.f};

    for (int k0 = 0; k0 < HIDDEN; k0 += 32) {
        short8 av0 = *reinterpret_cast<const short8*>(A + (size_t)(m0 + row)      * HIDDEN + k0 + col8);
        short8 av1 = *reinterpret_cast<const short8*>(A + (size_t)(m0 + row + 64) * HIDDEN + k0 + col8);
        const float* w0 = Wt + (size_t)(n0 + row) * HIDDEN + k0 + col8;
        float4 w00 = reinterpret_cast<const float4*>(w0)[0];
        float4 w01 = reinterpret_cast<const float4*>(w0)[1];
        __syncthreads();
        *reinterpret_cast<short8*>(&As[row][col8])      = av0;
        *reinterpret_cast<short8*>(&As[row + 64][col8]) = av1;
        {
            union { unsigned int u[4]; short8 s; } pk;
            pk.u[0] = cvtpk(w00.x, w00.y);
            pk.u[1] = cvtpk(w00.z, w00.w);
            pk.u[2] = cvtpk(w01.x, w01.y);
            pk.u[3] = cvtpk(w01.z, w01.w);
            *reinterpret_cast<short8*>(&Bs[row][col8]) = pk.s;
        }
        __syncthreads();
        short8 af[2], bfr[4];
#pragma unroll
        for (int i = 0; i < 2; i++) af[i]  = *reinterpret_cast<const short8*>(&As[wm + i * 16 + lr][lk]);
#pragma unroll
        for (int j = 0; j < 4; j++) bfr[j] = *reinterpret_cast<const short8*>(&Bs[j * 16 + lr][lk]);
#pragma unroll
        for (int i = 0; i < 2; i++)
#pragma unroll
            for (int j = 0; j < 4; j++)
                acc[i][j] = __builtin_amdgcn_mfma_f32_16x16x32_bf16(af[i], bfr[j], acc[i][j], 0, 0, 0);
    }

#pragma unroll
    for (int i = 0; i < 2; i++) {
        int mrow = m0 + wm + i * 16 + (lane >> 4) * 4;
#pragma unroll
        for (int j = 0; j < 4; j++) {
            int ncol = n0 + j * 16 + lr;
            float bvv = bias[ncol];
#pragma unroll
            for (int r = 0; r < 4; r++)
                O[(size_t)(mrow + r) * HIDDEN + ncol] = acc[i][j][r] + bvv;
        }
    }
}

// ---------------------------------------------------------------- flash attention v7
// 2-wave blocks (128 thr), 32 q/wave, 64 q/block, grid 32x32=1024 -> 4 blocks/CU.
// K in LDS (double-buffered, global_load_lds, both-sides XOR swizzle); V read DIRECTLY
// from global (L2-resident per XCD head-slice) - drops V staging + V LDS reads.
// Psh per-wave [32][64] XOR-swizzled; P packed via v_cvt_pk_bf16_f32 (union, TBAA-safe).
// Q:[B,H,S,D] bf16 PRE-SCALED by 0.125*log2e; K:[B,H,S,D]; Vt:[B,H,D,S]; Y:[B,S,HIDDEN] bf16.
__global__ __launch_bounds__(128, 2) void attn_kernel(const unsigned short* __restrict__ Qb,
                                                      const unsigned short* __restrict__ Kb,
                                                      const unsigned short* __restrict__ Vt,
                                                      unsigned short* __restrict__ Yb) {
    __shared__ __attribute__((aligned(16))) unsigned short Ksh[2][64 * 64];   // 16 KB
    __shared__ __attribute__((aligned(16))) unsigned short Psh[2][32][64];    // 8 KB

    const int t    = threadIdx.x;
    const int lane = t & 63;
    const int wave = t >> 6;                                 // 0..1
    // bijective XCD grouping: fid&7 -> XCD slot; each slot covers 4 heads
    const int fid  = blockIdx.y * gridDim.x + blockIdx.x;    // 0..1023
    const int qblk = (fid >> 3) & 31;
    const int bh   = (fid & 7) * 4 + (fid >> 8);
    const int b_ = bh >> 4, h_ = bh & 15;
    const int qbase = qblk * 64 + wave * 32;
    const unsigned short* Qp = Qb + (size_t)bh * SS * DK;
    const unsigned short* Kp = Kb + (size_t)bh * SS * DK;
    const unsigned short* Vp = Vt + (size_t)bh * DK * SS;
    const int lr = lane & 15;
    const int g  = lane >> 4;
    const int sr = lane >> 3;                 // 0..7
    const int cs = (lane & 7) ^ sr;           // pre-swizzled source 16B chunk

    // Q B-frags (q cols qbase+qh*16+lr, d halves)
    short8 bq[2][2];
#pragma unroll
    for (int qh = 0; qh < 2; qh++)
#pragma unroll
        for (int dh = 0; dh < 2; dh++)
            bq[qh][dh] = *reinterpret_cast<const short8*>(
                Qp + (size_t)(qbase + qh * 16 + lr) * DK + dh * 32 + g * 8);

    f32x4 accd[4][2];
#pragma unroll
    for (int dt = 0; dt < 4; dt++)
#pragma unroll
        for (int qh = 0; qh < 2; qh++) accd[dt][qh] = f32x4{0.f, 0.f, 0.f, 0.f};
    float mi[2] = {-INFINITY, -INFINITY};
    float li[2] = {0.f, 0.f};

    // each wave stages 32 K-rows: 4 issues x (64 lanes x 16B = 8 rows)
#define STAGEK(BUF, KV0) do {                                                                \
    _Pragma("unroll")                                                                        \
    for (int j = 0; j < 4; j++)                                                              \
        __builtin_amdgcn_global_load_lds(                                                    \
            (const __attribute__((address_space(1))) unsigned int*)(Kp + (size_t)((KV0) + wave * 32 + j * 8 + sr) * DK + cs * 8), \
            (__attribute__((address_space(3))) unsigned int*)&Ksh[BUF][(wave * 32 + j * 8) * 64], 16, 0, 0); \
} while (0)

    STAGEK(0, 0);
    __syncthreads();

    for (int kv0 = 0; kv0 < SS; kv0 += 64) {
        const int cur = (kv0 >> 6) & 1;
        if (kv0 + 64 < SS) STAGEK(cur ^ 1, kv0 + 64);

        // K frags from LDS: row kv = tt*16+lr, d-chunk (h*4+g) XOR-swizzled by row
        short8 kf[4][2];
#pragma unroll
        for (int tt = 0; tt < 4; tt++)
#pragma unroll
            for (int h = 0; h < 2; h++)
                kf[tt][h] = *reinterpret_cast<const short8*>(
                    &Ksh[cur][(tt * 16 + lr) * 64 + (((h * 4 + g) ^ (lr & 7)) << 3)]);

        // V A-frags straight from global (issued early; consumed after softmax)
        short8 vv[4][2];
#pragma unroll
        for (int dt = 0; dt < 4; dt++)
#pragma unroll
            for (int h2 = 0; h2 < 2; h2++)
                vv[dt][h2] = *reinterpret_cast<const short8*>(
                    Vp + (size_t)(dt * 16 + lr) * SS + kv0 + h2 * 32 + g * 8);

        // QK^T -> S^T[kv][q]: lane holds kv = tt*16 + 4g + r for q-col = qh*16+lr
        f32x4 sv[2][4];
#pragma unroll
        for (int qh = 0; qh < 2; qh++)
#pragma unroll
            for (int tt = 0; tt < 4; tt++) {
                f32x4 z = f32x4{0.f, 0.f, 0.f, 0.f};
                z = __builtin_amdgcn_mfma_f32_16x16x32_bf16(kf[tt][0], bq[qh][0], z, 0, 0, 0);
                z = __builtin_amdgcn_mfma_f32_16x16x32_bf16(kf[tt][1], bq[qh][1], z, 0, 0, 0);
                sv[qh][tt] = z;
            }

        // online softmax (exp2 domain) per q-half
#pragma unroll
        for (int qh = 0; qh < 2; qh++) {
            float vmax = sv[qh][0][0];
#pragma unroll
            for (int tt = 0; tt < 4; tt++)
#pragma unroll
                for (int r = 0; r < 4; r++) vmax = fmaxf(vmax, sv[qh][tt][r]);
            vmax = fmaxf(vmax, __shfl_xor(vmax, 16));
            vmax = fmaxf(vmax, __shfl_xor(vmax, 32));
            if (!__all(vmax <= mi[qh] + 8.0f)) {
                float mnew = fmaxf(mi[qh], vmax);
                float sc = __builtin_amdgcn_exp2f(mi[qh] - mnew);
                li[qh] *= sc;
#pragma unroll
                for (int dt = 0; dt < 4; dt++)
#pragma unroll
                    for (int r = 0; r < 4; r++) accd[dt][qh][r] *= sc;
                mi[qh] = mnew;
            }
            float p[16];
            float rs = 0.f;
#pragma unroll
            for (int tt = 0; tt < 4; tt++)
#pragma unroll
                for (int r = 0; r < 4; r++) {
                    p[tt * 4 + r] = __builtin_amdgcn_exp2f(sv[qh][tt][r] - mi[qh]);
                    rs += p[tt * 4 + r];
                }
            rs += __shfl_xor(rs, 16);
            rs += __shfl_xor(rs, 32);
            li[qh] += rs;
            // pack P[kv][q]: row q, kv byte 32tt+8g -> chunk (2tt+(g>>1))^(row&7), half g&1.
            // cvt_pk in registers, stored as ushort4_t (TBAA-compatible with short8 reads).
#pragma unroll
            for (int tt = 0; tt < 4; tt++) {
                union { unsigned int u[2]; ushort4_t s; } pk;
                pk.u[0] = cvtpk(p[tt * 4 + 0], p[tt * 4 + 1]);
                pk.u[1] = cvtpk(p[tt * 4 + 2], p[tt * 4 + 3]);
                int cw = (2 * tt + (g >> 1)) ^ (lr & 7);
                *reinterpret_cast<ushort4_t*>(&Psh[wave][qh * 16 + lr][cw * 8 + (g & 1) * 4]) = pk.s;
            }
        }

        // fence: P-writes above must not be reordered against pf reads below
        __builtin_amdgcn_sched_barrier(0);

        // P B-frags: chunk h*4+g of row q, same XOR
        short8 pf[2][2];
#pragma unroll
        for (int qh = 0; qh < 2; qh++)
#pragma unroll
            for (int h = 0; h < 2; h++)
                pf[qh][h] = *reinterpret_cast<const short8*>(
                    &Psh[wave][qh * 16 + lr][((h * 4 + g) ^ (lr & 7)) * 8]);

        // PV: accd[dt][qh] += V^T[d][kv] * P[kv][q]
#pragma unroll
        for (int dt = 0; dt < 4; dt++)
#pragma unroll
            for (int qh = 0; qh < 2; qh++) {
                accd[dt][qh] = __builtin_amdgcn_mfma_f32_16x16x32_bf16(vv[dt][0], pf[qh][0], accd[dt][qh], 0, 0, 0);
                accd[dt][qh] = __builtin_amdgcn_mfma_f32_16x16x32_bf16(vv[dt][1], pf[qh][1], accd[dt][qh], 0, 0, 0);
            }
        __syncthreads();
    }
#undef STAGEK

    float inv[2] = {1.0f / li[0], 1.0f / li[1]};
#pragma unroll
    for (int qh = 0; qh < 2; qh++) {
        size_t ob = ((size_t)b_ * SS + qbase + qh * 16 + lr) * HIDDEN + h_ * 64 + g * 4;
#pragma unroll
        for (int dt = 0; dt < 4; dt++) {
            ushort4_t o;
            o.x = f2bf(accd[dt][qh][0] * inv[qh]);
            o.y = f2bf(accd[dt][qh][1] * inv[qh]);
            o.z = f2bf(accd[dt][qh][2] * inv[qh]);
            o.w = f2bf(accd[dt][qh][3] * inv[qh]);
            *reinterpret_cast<ushort4_t*>(Yb + ob + dt * 16) = o;
        }
    }
}

// ---------------------------------------------------------------- launch
extern "C" void kernel_launch(void* const* d_in, const int* in_sizes, int n_in,
                              void* d_out, int out_size, void* d_ws, size_t ws_size,
                              hipStream_t stream) {
    const float* query = (const float*)d_in[0];
    const float* key_  = (const float*)d_in[1];
    const float* value = (const float*)d_in[2];
    const float* w_q = (const float*)d_in[3];
    const float* b_q = (const float*)d_in[4];
    const float* w_k = (const float*)d_in[5];
    const float* b_k = (const float*)d_in[6];
    const float* w_v = (const float*)d_in[7];
    const float* b_v = (const float*)d_in[8];
    const float* w_o = (const float*)d_in[9];
    const float* b_o = (const float*)d_in[10];

    const size_t SZ_X = (size_t)MROWS * HIDDEN * 2;   // 8 MiB
    const size_t SZ_W = (size_t)HIDDEN * HIDDEN * 2;  // 2 MiB
    char* ws = (char*)d_ws;
    unsigned short* Xq = (unsigned short*)(ws);
    unsigned short* Xk = (unsigned short*)(ws + SZ_X);
    unsigned short* Xv = (unsigned short*)(ws + 2 * SZ_X);
    unsigned short* Wq = (unsigned short*)(ws + 3 * SZ_X);
    unsigned short* Wk = (unsigned short*)(ws + 3 * SZ_X + SZ_W);
    unsigned short* Wv = (unsigned short*)(ws + 3 * SZ_X + 2 * SZ_W);
    unsigned short* Qb  = (unsigned short*)(ws + 3 * SZ_X + 3 * SZ_W);
    unsigned short* Kbf = (unsigned short*)(ws + 4 * SZ_X + 3 * SZ_W);
    unsigned short* Vt  = (unsigned short*)(ws + 5 * SZ_X + 3 * SZ_W);
    unsigned short* Yb  = (unsigned short*)(ws + 6 * SZ_X + 3 * SZ_W);

    // cast: 3*2^20 + 3*2^18 float4 elements = 15360 blocks exactly
    cast_all<<<15360, 256, 0, stream>>>(query, key_, value, w_q, w_k, w_v,
                                        Xq, Xk, Xv, Wq, Wk, Wv);

    const float SCALE_Q = 0.125f * 1.4426950408889634f;  // 1/sqrt(64) * log2(e), folded into Q
    gemm_qkv<<<dim3(8, 32, 3), 256, 0, stream>>>(
        Xq, Xk, Xv, Wq, Wk, Wv, b_q, b_k, b_v, Qb, Kbf, Vt, SCALE_Q);

    attn_kernel<<<dim3(32, 32), 128, 0, stream>>>(Qb, Kbf, Vt, Yb);

    gemm_o<<<dim3(16, 32), 256, 0, stream>>>(Yb, w_o, b_o, (float*)d_out);
}

// Round 8
// 132.312 us; speedup vs baseline: 1.1837x; 1.1830x over previous
//
#include <hip/hip_runtime.h>
#include <hip/hip_bf16.h>
#include <math.h>

#define HIDDEN 1024
#define HEADS 16
#define DK 64
#define BB 2
#define SS 2048
#define MROWS (BB*SS)  /* 4096 */

typedef __attribute__((ext_vector_type(8))) short short8;
typedef __attribute__((ext_vector_type(4))) float f32x4;
typedef __attribute__((ext_vector_type(16))) float f32x16;
typedef __attribute__((ext_vector_type(4))) unsigned short ushort4_t;

static __device__ __forceinline__ unsigned short f2bf(float f) {
    unsigned int u = __float_as_uint(f);
    u += 0x7fffu + ((u >> 16) & 1u);
    return (unsigned short)(u >> 16);
}

static __device__ __forceinline__ unsigned int cvtpk(float lo, float hi) {
    unsigned int r;
    asm volatile("v_cvt_pk_bf16_f32 %0, %1, %2" : "=v"(r) : "v"(lo), "v"(hi));
    return r;
}
// v_permlane32_swap_b32: exchanges high half of a with low half of b (both updated)
static __device__ __forceinline__ void swap32(unsigned int& a, unsigned int& b) {
    asm volatile("v_permlane32_swap_b32 %0, %1" : "+v"(a), "+v"(b));
}

// ---------------------------------------------------------------- cast fp32 -> bf16 (X q/k/v + W q/k/v)
__global__ __launch_bounds__(256) void cast_all(
    const float* __restrict__ q, const float* __restrict__ k, const float* __restrict__ v,
    const float* __restrict__ wq, const float* __restrict__ wk, const float* __restrict__ wv,
    unsigned short* __restrict__ Xq, unsigned short* __restrict__ Xk, unsigned short* __restrict__ Xv,
    unsigned short* __restrict__ Wq, unsigned short* __restrict__ Wk, unsigned short* __restrict__ Wv) {
    int i = blockIdx.x * 256 + threadIdx.x;   // float4 index; grid exact: 3*2^20 + 3*2^18
    const float* src; unsigned short* dst; int off;
    if (i < (3 << 20)) {
        int w = i >> 20; off = i & ((1 << 20) - 1);
        src = (w == 0) ? q : (w == 1) ? k : v;
        dst = (w == 0) ? Xq : (w == 1) ? Xk : Xv;
    } else {
        int j = i - (3 << 20);
        int w = j >> 18; off = j & ((1 << 18) - 1);
        src = (w == 0) ? wq : (w == 1) ? wk : wv;
        dst = (w == 0) ? Wq : (w == 1) ? Wk : Wv;
    }
    float4 f = reinterpret_cast<const float4*>(src)[off];
    ushort4_t o;
    o.x = f2bf(f.x); o.y = f2bf(f.y); o.z = f2bf(f.z); o.w = f2bf(f.w);
    reinterpret_cast<ushort4_t*>(dst)[off] = o;
}

// ---------------------------------------------------------------- batched QKV projection GEMM (bf16 in)
__global__ __launch_bounds__(256, 3) void gemm_qkv(
    const unsigned short* __restrict__ Xq, const unsigned short* __restrict__ Xk, const unsigned short* __restrict__ Xv,
    const unsigned short* __restrict__ Wq, const unsigned short* __restrict__ Wk, const unsigned short* __restrict__ Wv,
    const float* __restrict__ bq, const float* __restrict__ bk, const float* __restrict__ bv,
    unsigned short* __restrict__ Qb, unsigned short* __restrict__ Kb, unsigned short* __restrict__ Vt,
    float scale_q) {
    __shared__ unsigned short As[128][40];
    __shared__ unsigned short Bs[128][40];
    const int lid = blockIdx.x + 8 * (blockIdx.y + 32 * blockIdx.z);
    const int c = lid & 7, i2 = lid >> 3;
    const int nb = i2 & 7;
    const int band = c * 12 + (i2 >> 3);
    const int yb = band & 31;
    const int z  = band >> 5;
    const unsigned short* A  = (z == 0) ? Xq : (z == 1) ? Xk : Xv;
    const unsigned short* Wt = (z == 0) ? Wq : (z == 1) ? Wk : Wv;
    const float* bias = (z == 0) ? bq : (z == 1) ? bk : bv;
    unsigned short* O = (z == 0) ? Qb : (z == 1) ? Kb : Vt;
    const float oscale = (z == 0) ? scale_q : 1.0f;

    const int t    = threadIdx.x;
    const int lane = t & 63;
    const int wave = t >> 6;
    const int m0 = yb * 128;
    const int n0 = nb * 128;
    const int row  = t >> 2;
    const int col8 = (t & 3) * 8;

    const int wm = (wave >> 1) * 64;
    const int wn = (wave & 1) * 64;
    const int lr = lane & 15;
    const int lk = (lane >> 4) * 8;

    f32x4 acc[4][4];
#pragma unroll
    for (int i = 0; i < 4; i++)
#pragma unroll
        for (int j = 0; j < 4; j++) acc[i][j] = f32x4{0.f, 0.f, 0.f, 0.f};

    for (int k0 = 0; k0 < HIDDEN; k0 += 32) {
        short8 av0 = *reinterpret_cast<const short8*>(A  + (size_t)(m0 + row)      * HIDDEN + k0 + col8);
        short8 av1 = *reinterpret_cast<const short8*>(A  + (size_t)(m0 + row + 64) * HIDDEN + k0 + col8);
        short8 bv0 = *reinterpret_cast<const short8*>(Wt + (size_t)(n0 + row)      * HIDDEN + k0 + col8);
        short8 bv1 = *reinterpret_cast<const short8*>(Wt + (size_t)(n0 + row + 64) * HIDDEN + k0 + col8);
        __syncthreads();
        *reinterpret_cast<short8*>(&As[row][col8])      = av0;
        *reinterpret_cast<short8*>(&As[row + 64][col8]) = av1;
        *reinterpret_cast<short8*>(&Bs[row][col8])      = bv0;
        *reinterpret_cast<short8*>(&Bs[row + 64][col8]) = bv1;
        __syncthreads();
        short8 af[4], bfr[4];
#pragma unroll
        for (int i = 0; i < 4; i++) af[i]  = *reinterpret_cast<const short8*>(&As[wm + i * 16 + lr][lk]);
#pragma unroll
        for (int j = 0; j < 4; j++) bfr[j] = *reinterpret_cast<const short8*>(&Bs[wn + j * 16 + lr][lk]);
#pragma unroll
        for (int i = 0; i < 4; i++)
#pragma unroll
            for (int j = 0; j < 4; j++)
                acc[i][j] = __builtin_amdgcn_mfma_f32_16x16x32_bf16(af[i], bfr[j], acc[i][j], 0, 0, 0);
    }

#pragma unroll
    for (int i = 0; i < 4; i++) {
        int mrow = m0 + wm + i * 16 + (lane >> 4) * 4;
#pragma unroll
        for (int j = 0; j < 4; j++) {
            int ncol = n0 + wn + j * 16 + lr;
            float bvv = bias[ncol];
            int b_ = mrow >> 11;
            int h_ = ncol >> 6;
            int d_ = ncol & 63;
            if (z != 2) {   // Q/K: [B,H,S,D]
#pragma unroll
                for (int r = 0; r < 4; r++) {
                    int s_ = (mrow + r) & 2047;
                    O[(((size_t)(b_ * HEADS + h_)) * SS + s_) * DK + d_] = f2bf((acc[i][j][r] + bvv) * oscale);
                }
            } else {        // V: [B,H,D,S] pre-transposed
                int s0 = mrow & 2047;
                ushort4_t pk;
                pk.x = f2bf(acc[i][j][0] + bvv);
                pk.y = f2bf(acc[i][j][1] + bvv);
                pk.z = f2bf(acc[i][j][2] + bvv);
                pk.w = f2bf(acc[i][j][3] + bvv);
                *reinterpret_cast<ushort4_t*>(O + (((size_t)(b_ * HEADS + h_) * DK + d_) * SS + s0)) = pk;
            }
        }
    }
}

// ---------------------------------------------------------------- final O-projection GEMM, 128x64 tile
__global__ __launch_bounds__(256) void gemm_o(const unsigned short* __restrict__ A,
                                              const float* __restrict__ Wt,
                                              const float* __restrict__ bias,
                                              float* __restrict__ O) {
    __shared__ unsigned short As[128][40];
    __shared__ unsigned short Bs[64][40];
    const int lid = blockIdx.x + 16 * blockIdx.y;   // 0..511
    const int c = lid & 7, i2 = lid >> 3;
    const int nb = i2 & 15;
    const int band = c * 4 + (i2 >> 4);
    const int t    = threadIdx.x;
    const int lane = t & 63;
    const int wave = t >> 6;
    const int m0 = band * 128;
    const int n0 = nb * 64;
    const int row  = t >> 2;
    const int col8 = (t & 3) * 8;

    const int wm = wave * 32;
    const int lr = lane & 15;
    const int lk = (lane >> 4) * 8;

    f32x4 acc[2][4];
#pragma unroll
    for (int i = 0; i < 2; i++)
#pragma unroll
        for (int j = 0; j < 4; j++) acc[i][j] = f32x4{0.f, 0.f, 0.f, 0.f};

    for (int k0 = 0; k0 < HIDDEN; k0 += 32) {
        short8 av0 = *reinterpret_cast<const short8*>(A + (size_t)(m0 + row)      * HIDDEN + k0 + col8);
        short8 av1 = *reinterpret_cast<const short8*>(A + (size_t)(m0 + row + 64) * HIDDEN + k0 + col8);
        const float* w0 = Wt + (size_t)(n0 + row) * HIDDEN + k0 + col8;
        float4 w00 = reinterpret_cast<const float4*>(w0)[0];
        float4 w01 = reinterpret_cast<const float4*>(w0)[1];
        __syncthreads();
        *reinterpret_cast<short8*>(&As[row][col8])      = av0;
        *reinterpret_cast<short8*>(&As[row + 64][col8]) = av1;
        {
            union { unsigned int u[4]; short8 s; } pk;
            pk.u[0] = cvtpk(w00.x, w00.y);
            pk.u[1] = cvtpk(w00.z, w00.w);
            pk.u[2] = cvtpk(w01.x, w01.y);
            pk.u[3] = cvtpk(w01.z, w01.w);
            *reinterpret_cast<short8*>(&Bs[row][col8]) = pk.s;
        }
        __syncthreads();
        short8 af[2], bfr[4];
#pragma unroll
        for (int i = 0; i < 2; i++) af[i]  = *reinterpret_cast<const short8*>(&As[wm + i * 16 + lr][lk]);
#pragma unroll
        for (int j = 0; j < 4; j++) bfr[j] = *reinterpret_cast<const short8*>(&Bs[j * 16 + lr][lk]);
#pragma unroll
        for (int i = 0; i < 2; i++)
#pragma unroll
            for (int j = 0; j < 4; j++)
                acc[i][j] = __builtin_amdgcn_mfma_f32_16x16x32_bf16(af[i], bfr[j], acc[i][j], 0, 0, 0);
    }

#pragma unroll
    for (int i = 0; i < 2; i++) {
        int mrow = m0 + wm + i * 16 + (lane >> 4) * 4;
#pragma unroll
        for (int j = 0; j < 4; j++) {
            int ncol = n0 + j * 16 + lr;
            float bvv = bias[ncol];
#pragma unroll
            for (int r = 0; r < 4; r++)
                O[(size_t)(mrow + r) * HIDDEN + ncol] = acc[i][j][r] + bvv;
        }
    }
}

// ---------------------------------------------------------------- flash attention v8: 32x32x16 MFMA, P in registers
// 4 waves/block, 32 q/wave (128 q/block), KVBLK=64, grid 512 (XCD-grouped: 4 heads/XCD).
// K,V LDS-staged (double-buffered, global_load_lds, both-sides XOR swizzle) - IDENTICAL to v5.
// QK^T swapped: sv = mfma32(K, Q) -> S^T C-layout: col=lane&31=q, row kv=(r&3)+8*(r>>2)+4*hi.
// Softmax: in-lane over 32 + one shfl_xor(32). P->PV A-frags fully in-register:
// frag{w0,w2} = permlane32_swap(cvtpk(p0,p1), cvtpk(p4,p5)); frag{w1,w3} = swap(cvtpk(p2,p3), cvtpk(p6,p7)).
// PV: acc[dt] = mfma32(P, V); out C: col=lane&31=d(within tile), row q=(r&3)+8*(r>>2)+4*hi.
// li redistributed once at end via per-wave 32-float LDS.
__global__ __launch_bounds__(256, 2) void attn_kernel(const unsigned short* __restrict__ Qb,
                                                      const unsigned short* __restrict__ Kb,
                                                      const unsigned short* __restrict__ Vt,
                                                      unsigned short* __restrict__ Yb) {
    __shared__ __attribute__((aligned(16))) unsigned short Ksh[2][64 * 64];   // 16 KB
    __shared__ __attribute__((aligned(16))) unsigned short Vsh[2][64 * 64];   // 16 KB
    __shared__ float Lsh[4][32];

    const int t    = threadIdx.x;
    const int lane = t & 63;
    const int wave = t >> 6;
    // bijective XCD grouping over 512 blocks: c=fid&7 -> XCD; each slot owns 4 heads
    const int fid  = blockIdx.x;               // 0..511
    const int qblk = (fid >> 3) & 15;
    const int bh   = (fid & 7) * 4 + (fid >> 7);
    const int b_ = bh >> 4, h_ = bh & 15;
    const int qbase = qblk * 128 + wave * 32;
    const unsigned short* Qp = Qb + (size_t)bh * SS * DK;
    const unsigned short* Kp = Kb + (size_t)bh * SS * DK;
    const unsigned short* Vp = Vt + (size_t)bh * DK * SS;
    const int lq = lane & 31;
    const int hi = lane >> 5;
    const int sr = lane >> 3;                 // 0..7
    const int cs = (lane & 7) ^ sr;           // pre-swizzled source 16B chunk

    // Q B-frags: chain c covers d = 16c + 8*hi + idx (16B contiguous)
    short8 qf[4];
#pragma unroll
    for (int c = 0; c < 4; c++)
        qf[c] = *reinterpret_cast<const short8*>(Qp + (size_t)(qbase + lq) * DK + c * 16 + hi * 8);

    f32x16 acc0 = {0.f}, acc1 = {0.f};
#pragma unroll
    for (int r = 0; r < 16; r++) { acc0[r] = 0.f; acc1[r] = 0.f; }
    float mi = -INFINITY, li = 0.f;

#define STAGE(BUF, KV0) do {                                                                 \
    __builtin_amdgcn_global_load_lds(                                                        \
        (const __attribute__((address_space(1))) unsigned int*)(Kp + (size_t)((KV0) + wave * 16 + sr) * DK + cs * 8), \
        (__attribute__((address_space(3))) unsigned int*)&Ksh[BUF][(wave * 16) * 64], 16, 0, 0); \
    __builtin_amdgcn_global_load_lds(                                                        \
        (const __attribute__((address_space(1))) unsigned int*)(Kp + (size_t)((KV0) + wave * 16 + 8 + sr) * DK + cs * 8), \
        (__attribute__((address_space(3))) unsigned int*)&Ksh[BUF][(wave * 16 + 8) * 64], 16, 0, 0); \
    __builtin_amdgcn_global_load_lds(                                                        \
        (const __attribute__((address_space(1))) unsigned int*)(Vp + (size_t)(wave * 16 + sr) * SS + (KV0) + cs * 8), \
        (__attribute__((address_space(3))) unsigned int*)&Vsh[BUF][(wave * 16) * 64], 16, 0, 0); \
    __builtin_amdgcn_global_load_lds(                                                        \
        (const __attribute__((address_space(1))) unsigned int*)(Vp + (size_t)(wave * 16 + 8 + sr) * SS + (KV0) + cs * 8), \
        (__attribute__((address_space(3))) unsigned int*)&Vsh[BUF][(wave * 16 + 8) * 64], 16, 0, 0); \
} while (0)

    STAGE(0, 0);
    __syncthreads();

    for (int kv0 = 0; kv0 < SS; kv0 += 64) {
        const int cur = (kv0 >> 6) & 1;
        if (kv0 + 64 < SS) STAGE(cur ^ 1, kv0 + 64);

        // ---- QK^T: two 32x32 S^T tiles (kv 0-31, 32-63), chained over d (4x K=16)
        f32x16 sv0, sv1;
#pragma unroll
        for (int r = 0; r < 16; r++) { sv0[r] = 0.f; sv1[r] = 0.f; }
#pragma unroll
        for (int c = 0; c < 4; c++) {
            short8 kf0 = *reinterpret_cast<const short8*>(
                &Ksh[cur][lq * 64 + (((2 * c + hi) ^ (lq & 7)) << 3)]);
            short8 kf1 = *reinterpret_cast<const short8*>(
                &Ksh[cur][(32 + lq) * 64 + (((2 * c + hi) ^ (lq & 7)) << 3)]);
            sv0 = __builtin_amdgcn_mfma_f32_32x32x16_bf16(kf0, qf[c], sv0, 0, 0, 0);
            sv1 = __builtin_amdgcn_mfma_f32_32x32x16_bf16(kf1, qf[c], sv1, 0, 0, 0);
        }

        // ---- online softmax (exp2 domain), q = lq column; halves combine via shfl_xor(32)
        float vmax = sv0[0];
#pragma unroll
        for (int r = 0; r < 16; r++) { vmax = fmaxf(vmax, sv0[r]); vmax = fmaxf(vmax, sv1[r]); }
        vmax = fmaxf(vmax, __shfl_xor(vmax, 32));
        if (!__all(vmax <= mi + 8.0f)) {
            float mnew = fmaxf(mi, vmax);
            float sc = __builtin_amdgcn_exp2f(mi - mnew);
            li *= sc;
            acc0 = acc0 * sc;
            acc1 = acc1 * sc;
            mi = mnew;
        }
        float pt[2][16];
        float rs = 0.f;
#pragma unroll
        for (int r = 0; r < 16; r++) {
            pt[0][r] = __builtin_amdgcn_exp2f(sv0[r] - mi);
            pt[1][r] = __builtin_amdgcn_exp2f(sv1[r] - mi);
            rs += pt[0][r] + pt[1][r];
        }
        rs += __shfl_xor(rs, 32);
        li += rs;

        // ---- P -> PV A-frags, fully in-register (cvt_pk + permlane32_swap)
        short8 fragP[4];
#pragma unroll
        for (int tt = 0; tt < 2; tt++)
#pragma unroll
            for (int cl = 0; cl < 2; cl++) {
                unsigned int w0 = cvtpk(pt[tt][cl * 8 + 0], pt[tt][cl * 8 + 1]);
                unsigned int w1 = cvtpk(pt[tt][cl * 8 + 2], pt[tt][cl * 8 + 3]);
                unsigned int w2 = cvtpk(pt[tt][cl * 8 + 4], pt[tt][cl * 8 + 5]);
                unsigned int w3 = cvtpk(pt[tt][cl * 8 + 6], pt[tt][cl * 8 + 7]);
                swap32(w0, w2);
                swap32(w1, w3);
                union { unsigned int u[4]; short8 s; } f;
                f.u[0] = w0; f.u[1] = w1; f.u[2] = w2; f.u[3] = w3;
                fragP[tt * 2 + cl] = f.s;
            }

        // ---- PV: acc[dt] += P * V, chained over kv (4x K=16), V B-frags from LDS
#pragma unroll
        for (int cc = 0; cc < 4; cc++) {
            short8 vf0 = *reinterpret_cast<const short8*>(
                &Vsh[cur][lq * 64 + (((2 * cc + hi) ^ (lq & 7)) << 3)]);
            short8 vf1 = *reinterpret_cast<const short8*>(
                &Vsh[cur][(32 + lq) * 64 + (((2 * cc + hi) ^ (lq & 7)) << 3)]);
            acc0 = __builtin_amdgcn_mfma_f32_32x32x16_bf16(fragP[cc], vf0, acc0, 0, 0, 0);
            acc1 = __builtin_amdgcn_mfma_f32_32x32x16_bf16(fragP[cc], vf1, acc1, 0, 0, 0);
        }
        __syncthreads();
    }
#undef STAGE

    // ---- epilogue: redistribute 1/li across the hi-halves via per-wave LDS
    if (lane < 32) Lsh[wave][lq] = 1.0f / li;
    __syncthreads();
#pragma unroll
    for (int r = 0; r < 16; r++) {
        int qr = (r & 3) + 8 * (r >> 2) + 4 * hi;
        float inv = Lsh[wave][qr];
        size_t base = ((size_t)b_ * SS + qbase + qr) * HIDDEN + h_ * 64 + lq;
        Yb[base]      = f2bf(acc0[r] * inv);
        Yb[base + 32] = f2bf(acc1[r] * inv);
    }
}

// ---------------------------------------------------------------- launch
extern "C" void kernel_launch(void* const* d_in, const int* in_sizes, int n_in,
                              void* d_out, int out_size, void* d_ws, size_t ws_size,
                              hipStream_t stream) {
    const float* query = (const float*)d_in[0];
    const float* key_  = (const float*)d_in[1];
    const float* value = (const float*)d_in[2];
    const float* w_q = (const float*)d_in[3];
    const float* b_q = (const float*)d_in[4];
    const float* w_k = (const float*)d_in[5];
    const float* b_k = (const float*)d_in[6];
    const float* w_v = (const float*)d_in[7];
    const float* b_v = (const float*)d_in[8];
    const float* w_o = (const float*)d_in[9];
    const float* b_o = (const float*)d_in[10];

    const size_t SZ_X = (size_t)MROWS * HIDDEN * 2;   // 8 MiB
    const size_t SZ_W = (size_t)HIDDEN * HIDDEN * 2;  // 2 MiB
    char* ws = (char*)d_ws;
    unsigned short* Xq = (unsigned short*)(ws);
    unsigned short* Xk = (unsigned short*)(ws + SZ_X);
    unsigned short* Xv = (unsigned short*)(ws + 2 * SZ_X);
    unsigned short* Wq = (unsigned short*)(ws + 3 * SZ_X);
    unsigned short* Wk = (unsigned short*)(ws + 3 * SZ_X + SZ_W);
    unsigned short* Wv = (unsigned short*)(ws + 3 * SZ_X + 2 * SZ_W);
    unsigned short* Qb  = (unsigned short*)(ws + 3 * SZ_X + 3 * SZ_W);
    unsigned short* Kbf = (unsigned short*)(ws + 4 * SZ_X + 3 * SZ_W);
    unsigned short* Vt  = (unsigned short*)(ws + 5 * SZ_X + 3 * SZ_W);
    unsigned short* Yb  = (unsigned short*)(ws + 6 * SZ_X + 3 * SZ_W);

    cast_all<<<15360, 256, 0, stream>>>(query, key_, value, w_q, w_k, w_v,
                                        Xq, Xk, Xv, Wq, Wk, Wv);

    const float SCALE_Q = 0.125f * 1.4426950408889634f;  // 1/sqrt(64) * log2(e), folded into Q
    gemm_qkv<<<dim3(8, 32, 3), 256, 0, stream>>>(
        Xq, Xk, Xv, Wq, Wk, Wv, b_q, b_k, b_v, Qb, Kbf, Vt, SCALE_Q);

    attn_kernel<<<dim3(512), 256, 0, stream>>>(Qb, Kbf, Vt, Yb);

    gemm_o<<<dim3(16, 32), 256, 0, stream>>>(Yb, w_o, b_o, (float*)d_out);
}

// Round 9
// 129.086 us; speedup vs baseline: 1.2133x; 1.0250x over previous
//
#include <hip/hip_runtime.h>
#include <hip/hip_bf16.h>
#include <math.h>

#define HIDDEN 1024
#define HEADS 16
#define DK 64
#define BB 2
#define SS 2048
#define MROWS (BB*SS)  /* 4096 */

typedef __attribute__((ext_vector_type(8))) short short8;
typedef __attribute__((ext_vector_type(4))) float f32x4;
typedef __attribute__((ext_vector_type(16))) float f32x16;
typedef __attribute__((ext_vector_type(4))) unsigned short ushort4_t;

static __device__ __forceinline__ unsigned short f2bf(float f) {
    unsigned int u = __float_as_uint(f);
    u += 0x7fffu + ((u >> 16) & 1u);
    return (unsigned short)(u >> 16);
}
static __device__ __forceinline__ float bf2f(unsigned short s) {
    return __uint_as_float(((unsigned int)s) << 16);
}

static __device__ __forceinline__ unsigned int cvtpk(float lo, float hi) {
    unsigned int r;
    asm volatile("v_cvt_pk_bf16_f32 %0, %1, %2" : "=v"(r) : "v"(lo), "v"(hi));
    return r;
}
// v_permlane32_swap_b32: exchanges high half of a with low half of b (both updated)
static __device__ __forceinline__ void swap32(unsigned int& a, unsigned int& b) {
    asm volatile("v_permlane32_swap_b32 %0, %1" : "+v"(a), "+v"(b));
}
// pack 8 f32 (two float4) -> short8 of bf16, register-only (TBAA-safe)
static __device__ __forceinline__ short8 pack_bf16x8(float4 lo, float4 hi) {
    union { unsigned int u[4]; short8 s; } r;
    r.u[0] = cvtpk(lo.x, lo.y);
    r.u[1] = cvtpk(lo.z, lo.w);
    r.u[2] = cvtpk(hi.x, hi.y);
    r.u[3] = cvtpk(hi.z, hi.w);
    return r.s;
}

// ---------------------------------------------------------------- batched QKV projection GEMM
// fp32 inputs, cast fused into LDS staging (cvtpk pattern proven in gemm_o since r6).
// 768 blocks XCD-swizzled: all 8 n-blocks of an A-band co-reside on one XCD (A fp32
// re-reads hit L2); W reused across the XCD's 12 bands.
__global__ __launch_bounds__(256, 3) void gemm_qkv(
    const float* __restrict__ Xq, const float* __restrict__ Xk, const float* __restrict__ Xv,
    const float* __restrict__ Wq, const float* __restrict__ Wk, const float* __restrict__ Wv,
    const float* __restrict__ bq, const float* __restrict__ bk, const float* __restrict__ bv,
    unsigned short* __restrict__ Qb, unsigned short* __restrict__ Kb, unsigned short* __restrict__ Vt,
    float scale_q) {
    __shared__ unsigned short As[128][40];
    __shared__ unsigned short Bs[128][40];
    const int lid = blockIdx.x + 8 * (blockIdx.y + 32 * blockIdx.z);
    const int c = lid & 7, i2 = lid >> 3;
    const int nb = i2 & 7;
    const int band = c * 12 + (i2 >> 3);
    const int yb = band & 31;
    const int z  = band >> 5;
    const float* A  = (z == 0) ? Xq : (z == 1) ? Xk : Xv;
    const float* Wt = (z == 0) ? Wq : (z == 1) ? Wk : Wv;
    const float* bias = (z == 0) ? bq : (z == 1) ? bk : bv;
    unsigned short* O = (z == 0) ? Qb : (z == 1) ? Kb : Vt;
    const float oscale = (z == 0) ? scale_q : 1.0f;

    const int t    = threadIdx.x;
    const int lane = t & 63;
    const int wave = t >> 6;
    const int m0 = yb * 128;
    const int n0 = nb * 128;
    const int row  = t >> 2;
    const int col8 = (t & 3) * 8;

    const int wm = (wave >> 1) * 64;
    const int wn = (wave & 1) * 64;
    const int lr = lane & 15;
    const int lk = (lane >> 4) * 8;

    f32x4 acc[4][4];
#pragma unroll
    for (int i = 0; i < 4; i++)
#pragma unroll
        for (int j = 0; j < 4; j++) acc[i][j] = f32x4{0.f, 0.f, 0.f, 0.f};

    for (int k0 = 0; k0 < HIDDEN; k0 += 32) {
        const float* a0 = A  + (size_t)(m0 + row)      * HIDDEN + k0 + col8;
        const float* a1 = A  + (size_t)(m0 + row + 64) * HIDDEN + k0 + col8;
        const float* w0 = Wt + (size_t)(n0 + row)      * HIDDEN + k0 + col8;
        const float* w1 = Wt + (size_t)(n0 + row + 64) * HIDDEN + k0 + col8;
        float4 a00 = reinterpret_cast<const float4*>(a0)[0];
        float4 a01 = reinterpret_cast<const float4*>(a0)[1];
        float4 a10 = reinterpret_cast<const float4*>(a1)[0];
        float4 a11 = reinterpret_cast<const float4*>(a1)[1];
        float4 w00 = reinterpret_cast<const float4*>(w0)[0];
        float4 w01 = reinterpret_cast<const float4*>(w0)[1];
        float4 w10 = reinterpret_cast<const float4*>(w1)[0];
        float4 w11 = reinterpret_cast<const float4*>(w1)[1];
        __syncthreads();
        *reinterpret_cast<short8*>(&As[row][col8])      = pack_bf16x8(a00, a01);
        *reinterpret_cast<short8*>(&As[row + 64][col8]) = pack_bf16x8(a10, a11);
        *reinterpret_cast<short8*>(&Bs[row][col8])      = pack_bf16x8(w00, w01);
        *reinterpret_cast<short8*>(&Bs[row + 64][col8]) = pack_bf16x8(w10, w11);
        __syncthreads();
        short8 af[4], bfr[4];
#pragma unroll
        for (int i = 0; i < 4; i++) af[i]  = *reinterpret_cast<const short8*>(&As[wm + i * 16 + lr][lk]);
#pragma unroll
        for (int j = 0; j < 4; j++) bfr[j] = *reinterpret_cast<const short8*>(&Bs[wn + j * 16 + lr][lk]);
#pragma unroll
        for (int i = 0; i < 4; i++)
#pragma unroll
            for (int j = 0; j < 4; j++)
                acc[i][j] = __builtin_amdgcn_mfma_f32_16x16x32_bf16(af[i], bfr[j], acc[i][j], 0, 0, 0);
    }

#pragma unroll
    for (int i = 0; i < 4; i++) {
        int mrow = m0 + wm + i * 16 + (lane >> 4) * 4;
#pragma unroll
        for (int j = 0; j < 4; j++) {
            int ncol = n0 + wn + j * 16 + lr;
            float bvv = bias[ncol];
            int b_ = mrow >> 11;
            int h_ = ncol >> 6;
            int d_ = ncol & 63;
            if (z != 2) {   // Q/K: [B,H,S,D]
#pragma unroll
                for (int r = 0; r < 4; r++) {
                    int s_ = (mrow + r) & 2047;
                    O[(((size_t)(b_ * HEADS + h_)) * SS + s_) * DK + d_] = f2bf((acc[i][j][r] + bvv) * oscale);
                }
            } else {        // V: [B,H,D,S] pre-transposed
                int s0 = mrow & 2047;
                ushort4_t pk;
                pk.x = f2bf(acc[i][j][0] + bvv);
                pk.y = f2bf(acc[i][j][1] + bvv);
                pk.z = f2bf(acc[i][j][2] + bvv);
                pk.w = f2bf(acc[i][j][3] + bvv);
                *reinterpret_cast<ushort4_t*>(O + (((size_t)(b_ * HEADS + h_) * DK + d_) * SS + s0)) = pk;
            }
        }
    }
}

// ---------------------------------------------------------------- final O-projection GEMM, 128x64 tile
__global__ __launch_bounds__(256) void gemm_o(const unsigned short* __restrict__ A,
                                              const float* __restrict__ Wt,
                                              const float* __restrict__ bias,
                                              float* __restrict__ O) {
    __shared__ unsigned short As[128][40];
    __shared__ unsigned short Bs[64][40];
    const int lid = blockIdx.x + 16 * blockIdx.y;   // 0..511
    const int c = lid & 7, i2 = lid >> 3;
    const int nb = i2 & 15;
    const int band = c * 4 + (i2 >> 4);
    const int t    = threadIdx.x;
    const int lane = t & 63;
    const int wave = t >> 6;
    const int m0 = band * 128;
    const int n0 = nb * 64;
    const int row  = t >> 2;
    const int col8 = (t & 3) * 8;

    const int wm = wave * 32;
    const int lr = lane & 15;
    const int lk = (lane >> 4) * 8;

    f32x4 acc[2][4];
#pragma unroll
    for (int i = 0; i < 2; i++)
#pragma unroll
        for (int j = 0; j < 4; j++) acc[i][j] = f32x4{0.f, 0.f, 0.f, 0.f};

    for (int k0 = 0; k0 < HIDDEN; k0 += 32) {
        short8 av0 = *reinterpret_cast<const short8*>(A + (size_t)(m0 + row)      * HIDDEN + k0 + col8);
        short8 av1 = *reinterpret_cast<const short8*>(A + (size_t)(m0 + row + 64) * HIDDEN + k0 + col8);
        const float* w0 = Wt + (size_t)(n0 + row) * HIDDEN + k0 + col8;
        float4 w00 = reinterpret_cast<const float4*>(w0)[0];
        float4 w01 = reinterpret_cast<const float4*>(w0)[1];
        __syncthreads();
        *reinterpret_cast<short8*>(&As[row][col8])      = av0;
        *reinterpret_cast<short8*>(&As[row + 64][col8]) = av1;
        *reinterpret_cast<short8*>(&Bs[row][col8])      = pack_bf16x8(w00, w01);
        __syncthreads();
        short8 af[2], bfr[4];
#pragma unroll
        for (int i = 0; i < 2; i++) af[i]  = *reinterpret_cast<const short8*>(&As[wm + i * 16 + lr][lk]);
#pragma unroll
        for (int j = 0; j < 4; j++) bfr[j] = *reinterpret_cast<const short8*>(&Bs[j * 16 + lr][lk]);
#pragma unroll
        for (int i = 0; i < 2; i++)
#pragma unroll
            for (int j = 0; j < 4; j++)
                acc[i][j] = __builtin_amdgcn_mfma_f32_16x16x32_bf16(af[i], bfr[j], acc[i][j], 0, 0, 0);
    }

#pragma unroll
    for (int i = 0; i < 2; i++) {
        int mrow = m0 + wm + i * 16 + (lane >> 4) * 4;
#pragma unroll
        for (int j = 0; j < 4; j++) {
            int ncol = n0 + j * 16 + lr;
            float bvv = bias[ncol];
#pragma unroll
            for (int r = 0; r < 4; r++)
                O[(size_t)(mrow + r) * HIDDEN + ncol] = acc[i][j][r] + bvv;
        }
    }
}

// ---------------------------------------------------------------- flash attention v9: v8 inner loop + kv split-K (2 halves)
// grid 1024 = 32 bh x 16 qblk x 2 kvh -> 4 blocks/CU, 16 waves/CU (2x v8 occupancy).
// Each block: 4 waves x 32 q, kv range 1024 (16 steps of 64). Per-half normalized O -> Yb0/Yb1
// (bf16, [B,S,HIDDEN] layout) + (m, l) per (kvh,bh,q) -> ml. XCD grouping: XCD c owns bh 4c..4c+3
// (both halves) -> K/V 2 MB L2-resident. Inner loop byte-identical to v8.
__global__ __launch_bounds__(256, 4) void attn_kernel(const unsigned short* __restrict__ Qb,
                                                      const unsigned short* __restrict__ Kb,
                                                      const unsigned short* __restrict__ Vt,
                                                      unsigned short* __restrict__ Yb0,
                                                      unsigned short* __restrict__ Yb1,
                                                      float2* __restrict__ ml) {
    __shared__ __attribute__((aligned(16))) unsigned short Ksh[2][64 * 64];   // 16 KB
    __shared__ __attribute__((aligned(16))) unsigned short Vsh[2][64 * 64];   // 16 KB
    __shared__ float Lsh[4][32];

    const int t    = threadIdx.x;
    const int lane = t & 63;
    const int wave = t >> 6;
    // bijective decomposition: fid = c + 8*(qblk + 16*j); pair = c*8+j -> (bh, kvh)
    const int fid  = blockIdx.x;               // 0..1023
    const int c    = fid & 7;
    const int i    = fid >> 3;                 // 0..127
    const int qblk = i & 15;
    const int pair = c * 8 + (i >> 4);         // 0..63
    const int bh   = pair >> 1;
    const int kvh  = pair & 1;
    const int b_ = bh >> 4, h_ = bh & 15;
    const int qbase = qblk * 128 + wave * 32;
    const int kvbase = kvh << 10;
    const unsigned short* Qp = Qb + (size_t)bh * SS * DK;
    const unsigned short* Kp = Kb + (size_t)bh * SS * DK;
    const unsigned short* Vp = Vt + (size_t)bh * DK * SS;
    const int lq = lane & 31;
    const int hi = lane >> 5;
    const int sr = lane >> 3;                 // 0..7
    const int cs = (lane & 7) ^ sr;           // pre-swizzled source 16B chunk

    // Q B-frags: chain c covers d = 16c + 8*hi + idx (16B contiguous)
    short8 qf[4];
#pragma unroll
    for (int cc = 0; cc < 4; cc++)
        qf[cc] = *reinterpret_cast<const short8*>(Qp + (size_t)(qbase + lq) * DK + cc * 16 + hi * 8);

    f32x16 acc0, acc1;
#pragma unroll
    for (int r = 0; r < 16; r++) { acc0[r] = 0.f; acc1[r] = 0.f; }
    float mi = -INFINITY, li = 0.f;

#define STAGE(BUF, KV0) do {                                                                 \
    __builtin_amdgcn_global_load_lds(                                                        \
        (const __attribute__((address_space(1))) unsigned int*)(Kp + (size_t)((KV0) + wave * 16 + sr) * DK + cs * 8), \
        (__attribute__((address_space(3))) unsigned int*)&Ksh[BUF][(wave * 16) * 64], 16, 0, 0); \
    __builtin_amdgcn_global_load_lds(                                                        \
        (const __attribute__((address_space(1))) unsigned int*)(Kp + (size_t)((KV0) + wave * 16 + 8 + sr) * DK + cs * 8), \
        (__attribute__((address_space(3))) unsigned int*)&Ksh[BUF][(wave * 16 + 8) * 64], 16, 0, 0); \
    __builtin_amdgcn_global_load_lds(                                                        \
        (const __attribute__((address_space(1))) unsigned int*)(Vp + (size_t)(wave * 16 + sr) * SS + (KV0) + cs * 8), \
        (__attribute__((address_space(3))) unsigned int*)&Vsh[BUF][(wave * 16) * 64], 16, 0, 0); \
    __builtin_amdgcn_global_load_lds(                                                        \
        (const __attribute__((address_space(1))) unsigned int*)(Vp + (size_t)(wave * 16 + 8 + sr) * SS + (KV0) + cs * 8), \
        (__attribute__((address_space(3))) unsigned int*)&Vsh[BUF][(wave * 16 + 8) * 64], 16, 0, 0); \
} while (0)

    STAGE(0, kvbase);
    __syncthreads();

    for (int kv0 = kvbase; kv0 < kvbase + 1024; kv0 += 64) {
        const int cur = (kv0 >> 6) & 1;
        if (kv0 + 64 < kvbase + 1024) STAGE(cur ^ 1, kv0 + 64);

        // ---- QK^T: two 32x32 S^T tiles (kv 0-31, 32-63), chained over d (4x K=16)
        f32x16 sv0, sv1;
#pragma unroll
        for (int r = 0; r < 16; r++) { sv0[r] = 0.f; sv1[r] = 0.f; }
#pragma unroll
        for (int cc = 0; cc < 4; cc++) {
            short8 kf0 = *reinterpret_cast<const short8*>(
                &Ksh[cur][lq * 64 + (((2 * cc + hi) ^ (lq & 7)) << 3)]);
            short8 kf1 = *reinterpret_cast<const short8*>(
                &Ksh[cur][(32 + lq) * 64 + (((2 * cc + hi) ^ (lq & 7)) << 3)]);
            sv0 = __builtin_amdgcn_mfma_f32_32x32x16_bf16(kf0, qf[cc], sv0, 0, 0, 0);
            sv1 = __builtin_amdgcn_mfma_f32_32x32x16_bf16(kf1, qf[cc], sv1, 0, 0, 0);
        }

        // ---- online softmax (exp2 domain), q = lq column; halves combine via shfl_xor(32)
        float vmax = sv0[0];
#pragma unroll
        for (int r = 0; r < 16; r++) { vmax = fmaxf(vmax, sv0[r]); vmax = fmaxf(vmax, sv1[r]); }
        vmax = fmaxf(vmax, __shfl_xor(vmax, 32));
        if (!__all(vmax <= mi + 8.0f)) {
            float mnew = fmaxf(mi, vmax);
            float sc = __builtin_amdgcn_exp2f(mi - mnew);
            li *= sc;
            acc0 = acc0 * sc;
            acc1 = acc1 * sc;
            mi = mnew;
        }
        float pt[2][16];
        float rs = 0.f;
#pragma unroll
        for (int r = 0; r < 16; r++) {
            pt[0][r] = __builtin_amdgcn_exp2f(sv0[r] - mi);
            pt[1][r] = __builtin_amdgcn_exp2f(sv1[r] - mi);
            rs += pt[0][r] + pt[1][r];
        }
        rs += __shfl_xor(rs, 32);
        li += rs;

        // ---- P -> PV A-frags, fully in-register (cvt_pk + permlane32_swap)
        short8 fragP[4];
#pragma unroll
        for (int tt = 0; tt < 2; tt++)
#pragma unroll
            for (int cl = 0; cl < 2; cl++) {
                unsigned int w0 = cvtpk(pt[tt][cl * 8 + 0], pt[tt][cl * 8 + 1]);
                unsigned int w1 = cvtpk(pt[tt][cl * 8 + 2], pt[tt][cl * 8 + 3]);
                unsigned int w2 = cvtpk(pt[tt][cl * 8 + 4], pt[tt][cl * 8 + 5]);
                unsigned int w3 = cvtpk(pt[tt][cl * 8 + 6], pt[tt][cl * 8 + 7]);
                swap32(w0, w2);
                swap32(w1, w3);
                union { unsigned int u[4]; short8 s; } f;
                f.u[0] = w0; f.u[1] = w1; f.u[2] = w2; f.u[3] = w3;
                fragP[tt * 2 + cl] = f.s;
            }

        // ---- PV: acc += P * V, chained over kv (4x K=16), V B-frags from LDS
#pragma unroll
        for (int cc = 0; cc < 4; cc++) {
            short8 vf0 = *reinterpret_cast<const short8*>(
                &Vsh[cur][lq * 64 + (((2 * cc + hi) ^ (lq & 7)) << 3)]);
            short8 vf1 = *reinterpret_cast<const short8*>(
                &Vsh[cur][(32 + lq) * 64 + (((2 * cc + hi) ^ (lq & 7)) << 3)]);
            acc0 = __builtin_amdgcn_mfma_f32_32x32x16_bf16(fragP[cc], vf0, acc0, 0, 0, 0);
            acc1 = __builtin_amdgcn_mfma_f32_32x32x16_bf16(fragP[cc], vf1, acc1, 0, 0, 0);
        }
        __syncthreads();
    }
#undef STAGE

    // ---- epilogue: per-half normalized O + (m,l) bookkeeping
    unsigned short* Yp = kvh ? Yb1 : Yb0;
    if (lane < 32) {
        Lsh[wave][lq] = 1.0f / li;
        ml[(((size_t)kvh * 32 + bh) << 11) + qbase + lq] = float2{mi, li};
    }
    __syncthreads();
#pragma unroll
    for (int r = 0; r < 16; r++) {
        int qr = (r & 3) + 8 * (r >> 2) + 4 * hi;
        float inv = Lsh[wave][qr];
        size_t base = ((size_t)b_ * SS + qbase + qr) * HIDDEN + h_ * 64 + lq;
        Yp[base]      = f2bf(acc0[r] * inv);
        Yp[base + 32] = f2bf(acc1[r] * inv);
    }
}

// ---------------------------------------------------------------- combine the two kv-halves
// Yb = w0*Yb0 + w1*Yb1, w_i = l_i*2^(m_i-M)/sum. One short8 per thread (524288 threads).
__global__ __launch_bounds__(256) void combine_halves(const unsigned short* __restrict__ Yb0,
                                                      const unsigned short* __restrict__ Yb1,
                                                      const float2* __restrict__ ml,
                                                      unsigned short* __restrict__ Yb) {
    int j = blockIdx.x * 256 + threadIdx.x;       // short8 index over [B,S,128 chunks]
    int chunk = j & 127;
    int s = (j >> 7) & 2047;
    int b = j >> 18;
    int h = chunk >> 3;
    int bh = b * 16 + h;
    float2 m0 = ml[((size_t)bh << 11) + s];
    float2 m1 = ml[(((size_t)32 + bh) << 11) + s];
    float M = fmaxf(m0.x, m1.x);
    float l0 = m0.y * __builtin_amdgcn_exp2f(m0.x - M);
    float l1 = m1.y * __builtin_amdgcn_exp2f(m1.x - M);
    float inv = 1.0f / (l0 + l1);
    float w0 = l0 * inv, w1 = l1 * inv;
    short8 a = reinterpret_cast<const short8*>(Yb0)[j];
    short8 bb = reinterpret_cast<const short8*>(Yb1)[j];
    union { unsigned int u[4]; short8 s8; } o;
#pragma unroll
    for (int k = 0; k < 4; k++) {
        float lo = w0 * bf2f((unsigned short)a[2 * k])     + w1 * bf2f((unsigned short)bb[2 * k]);
        float hi = w0 * bf2f((unsigned short)a[2 * k + 1]) + w1 * bf2f((unsigned short)bb[2 * k + 1]);
        o.u[k] = cvtpk(lo, hi);
    }
    reinterpret_cast<short8*>(Yb)[j] = o.s8;
}

// ---------------------------------------------------------------- launch
extern "C" void kernel_launch(void* const* d_in, const int* in_sizes, int n_in,
                              void* d_out, int out_size, void* d_ws, size_t ws_size,
                              hipStream_t stream) {
    const float* query = (const float*)d_in[0];
    const float* key_  = (const float*)d_in[1];
    const float* value = (const float*)d_in[2];
    const float* w_q = (const float*)d_in[3];
    const float* b_q = (const float*)d_in[4];
    const float* w_k = (const float*)d_in[5];
    const float* b_k = (const float*)d_in[6];
    const float* w_v = (const float*)d_in[7];
    const float* b_v = (const float*)d_in[8];
    const float* w_o = (const float*)d_in[9];
    const float* b_o = (const float*)d_in[10];

    const size_t SZ_X = (size_t)MROWS * HIDDEN * 2;   // 8 MiB
    char* ws = (char*)d_ws;
    unsigned short* Qb  = (unsigned short*)(ws);
    unsigned short* Kbf = (unsigned short*)(ws + SZ_X);
    unsigned short* Vt  = (unsigned short*)(ws + 2 * SZ_X);
    unsigned short* Yb0 = (unsigned short*)(ws + 3 * SZ_X);
    unsigned short* Yb1 = (unsigned short*)(ws + 4 * SZ_X);
    unsigned short* Yb  = (unsigned short*)(ws + 5 * SZ_X);
    float2*         ml  = (float2*)(ws + 6 * SZ_X);   // 2*32*2048*8B = 1 MiB

    const float SCALE_Q = 0.125f * 1.4426950408889634f;  // 1/sqrt(64) * log2(e), folded into Q
    gemm_qkv<<<dim3(8, 32, 3), 256, 0, stream>>>(
        query, key_, value, w_q, w_k, w_v, b_q, b_k, b_v, Qb, Kbf, Vt, SCALE_Q);

    attn_kernel<<<dim3(1024), 256, 0, stream>>>(Qb, Kbf, Vt, Yb0, Yb1, ml);

    combine_halves<<<dim3(2048), 256, 0, stream>>>(Yb0, Yb1, ml, Yb);

    gemm_o<<<dim3(16, 32), 256, 0, stream>>>(Yb, w_o, b_o, (float*)d_out);
}